// Round 9
// baseline (492.508 us; speedup 1.0000x reference)
//
#include <hip/hip_runtime.h>

typedef __attribute__((ext_vector_type(8))) short short8;
typedef __attribute__((ext_vector_type(4))) float f32x4;
typedef __attribute__((ext_vector_type(2))) unsigned u32x2;
typedef __attribute__((ext_vector_type(4))) unsigned u32x4;
typedef unsigned short u16;

#define MFMA16 __builtin_amdgcn_mfma_f32_16x16x32_bf16

__device__ __forceinline__ u16 f2bf(float f) {
  unsigned u = __builtin_bit_cast(unsigned, f);
  u += 0x7fffu + ((u >> 16) & 1u);  // RTNE
  return (u16)(u >> 16);
}
// R4-proven manual pack (v_cvt_pk_bf16_f32 asm NaN'd in R5/R6 - banned)
__device__ __forceinline__ unsigned cvtpk(float a, float b) {
  return (unsigned)f2bf(a) | ((unsigned)f2bf(b) << 16);
}
__device__ __forceinline__ float bitf(unsigned u) {
  return __builtin_bit_cast(float, u);
}

// ---------------------------------------------------------------------------
// Setup: bf16 weights (q pre-scaled by scale*log2e), scaled bias, bias+mask
// table bmsw[w][h][tq(64)][tk(64)] bf16, pre-multiplied by log2e.
// Sentinel -30000 ONLY for tk>=49 (reduction axis).
// ws: qkvw@0 (98304B) projw@98304 (32768B) qkvbs@131072 (1536B)
//     bmsw@133120 (2097152B)
// ---------------------------------------------------------------------------
__global__ void setup_misc(const float* __restrict__ qkv_w,
                           const float* __restrict__ qkv_b,
                           const float* __restrict__ proj_w,
                           const float* __restrict__ mask,
                           const float* __restrict__ rpb,
                           const int* __restrict__ rel_idx,
                           u16* __restrict__ qkvw, u16* __restrict__ projw,
                           float* __restrict__ qkvbs, u16* __restrict__ bmsw) {
  const int i = blockIdx.x * 256 + threadIdx.x;
  const float LOG2E = 1.44269504088896f;
  const float qsc = 0.17677669529663687f * LOG2E;  // 1/sqrt(32) * log2e
  if (i < 384 * 128) qkvw[i] = f2bf(qkv_w[i] * (i < 16384 ? qsc : 1.f));
  if (i < 128 * 128) projw[i] = f2bf(proj_w[i]);
  if (i < 384) qkvbs[i] = qkv_b[i] * (i < 128 ? qsc : 1.f);
  {  // i in [0,1048576): w=i>>14 h=(i>>12)&3 tq=(i>>6)&63 tk=i&63
    const int w = i >> 14, h = (i >> 12) & 3, tq = (i >> 6) & 63, tk = i & 63;
    float v = 0.f;
    if (tk >= 49)
      v = -30000.f;  // mask the reduction axis only
    else if (tq < 49)
      v = (rpb[rel_idx[tq * 49 + tk] * 4 + h] + mask[w * 2401 + tq * 49 + tk]) *
          LOG2E;
    bmsw[i] = f2bf(v);
  }
}

// ---------------------------------------------------------------------------
// Fused Swin block. 1 block = 1 window, 8 waves: wave (h,u) = head h, half u.
// Per wave: phase1 3 GEMM tiles; phase2 S^T columns tqt in {2u,2u+1};
// phase3 matching PV half; phase4 one n-tile of the out-proj.
// LDS (49152 B), all rows XOR-swizzled (key row-determined both sides):
//  qT[h] @ h*8192        : [64 tok][64B: 32 d]   key=(row&3)<<4
//  kT[h] @ h*8192+4096   : [64 tok][64B: 32 d]   key=(row&3)<<4
//  P[h]  @ h*8192        : [64 tq][128B: 64 tk]  key=(row&7)<<4 (alias qT||kT)
//  VT[h] @ 32768+h*4096  : [32 d][128B: 64 tk]   key=(row&7)<<4
//  tmp   @ 32768         : [64 tok][256B: 128ch] key=(row&7)<<4 (alias all VT)
// ---------------------------------------------------------------------------
__global__ __launch_bounds__(512, 6) void swin_fused(
    const float* __restrict__ x, const float* __restrict__ qkvbs,
    const float* __restrict__ proj_b, const u16* __restrict__ qkvw,
    const u16* __restrict__ projw, const u16* __restrict__ bmsw,
    float* __restrict__ out) {
  __shared__ __align__(16) char smem[49152];
  const int b = blockIdx.x;
  const int tid = threadIdx.x;
  const int wv = tid >> 6;   // 0..7
  const int h = wv >> 1;     // head
  const int u = wv & 1;      // half
  const int lane = tid & 63;
  const int g = lane >> 4;
  const int ln = lane & 15;
  const unsigned key3 = (unsigned)((ln & 3) << 4);
  const unsigned key7 = (unsigned)((ln & 7) << 4);

  // ---------------- phase 1: x frags (A for v, B for q/k) ----------------
  short8 aa[4][4];
  const float* xb = x + (size_t)b * (49 * 128);
#pragma unroll
  for (int mt = 0; mt < 4; ++mt) {
    const int row = mt * 16 + ln;
#pragma unroll
    for (int kk = 0; kk < 4; ++kk) {
      if (row < 49) {
        const float* p = xb + row * 128 + kk * 32 + g * 8;
        const f32x4 u0 = *(const f32x4*)p;
        const f32x4 u1 = *(const f32x4*)(p + 4);
        u32x4 r = {cvtpk(u0[0], u0[1]), cvtpk(u0[2], u0[3]),
                   cvtpk(u1[0], u1[1]), cvtpk(u1[2], u1[3])};
        aa[mt][kk] = __builtin_bit_cast(short8, r);
      } else {
        u32x4 r = {0u, 0u, 0u, 0u};
        aa[mt][kk] = __builtin_bit_cast(short8, r);
      }
    }
  }
  // q^T, k^T: C[ch][tok] = mfma(W, x); this wave does Mt = u only
#pragma unroll
  for (int qk = 0; qk < 2; ++qk) {
    const int n = qk * 128 + h * 32 + u * 16 + ln;
    short8 wf[4];
#pragma unroll
    for (int kk = 0; kk < 4; ++kk)
      wf[kk] = *(const short8*)(qkvw + n * 128 + kk * 32 + g * 8);
    const f32x4 bq = *(const f32x4*)(qkvbs + qk * 128 + h * 32 + u * 16 + g * 4);
    f32x4 acc[4];
#pragma unroll
    for (int Nt = 0; Nt < 4; ++Nt) acc[Nt] = bq;
#pragma unroll
    for (int kk = 0; kk < 4; ++kk)
#pragma unroll
      for (int Nt = 0; Nt < 4; ++Nt)
        acc[Nt] = MFMA16(wf[kk], aa[Nt][kk], acc[Nt], 0, 0, 0);
#pragma unroll
    for (int Nt = 0; Nt < 4; ++Nt) {
      const int tok = Nt * 16 + ln;
      const u32x2 d2 = {cvtpk(acc[Nt][0], acc[Nt][1]),
                        cvtpk(acc[Nt][2], acc[Nt][3])};
      *(u32x2*)(smem + h * 8192 + qk * 4096 + tok * 64 +
                (((unsigned)(u * 32 + g * 8)) ^ key3)) = d2;
    }
  }
  // v: C[tok][d] = mfma(x, W) -> store VT[d][tok]; this wave dt = u
  {
    const int n = 256 + h * 32 + u * 16 + ln;
    short8 wf[4];
#pragma unroll
    for (int kk = 0; kk < 4; ++kk)
      wf[kk] = *(const short8*)(qkvw + n * 128 + kk * 32 + g * 8);
    const float bv = qkvbs[n];
    f32x4 acc[4];
#pragma unroll
    for (int mt = 0; mt < 4; ++mt) acc[mt] = f32x4{bv, bv, bv, bv};
#pragma unroll
    for (int kk = 0; kk < 4; ++kk)
#pragma unroll
      for (int mt = 0; mt < 4; ++mt)
        acc[mt] = MFMA16(aa[mt][kk], wf[kk], acc[mt], 0, 0, 0);
    const int d = u * 16 + ln;
#pragma unroll
    for (int mt = 0; mt < 4; ++mt) {
      const u32x2 d2 = {cvtpk(acc[mt][0], acc[mt][1]),
                        cvtpk(acc[mt][2], acc[mt][3])};
      *(u32x2*)(smem + 32768 + h * 4096 + d * 128 +
                (((unsigned)(mt * 32 + g * 8)) ^ key7)) = d2;
    }
  }
  __syncthreads();  // B1: q/k/VT complete (written by wave pairs)

  // ---------------- phase 2: S^T = mfma(k, q) + bias-as-C-init ----------
  // this wave: tqt = 2u + j, j in {0,1}
  const char* bmb = (const char*)(bmsw + ((size_t)((b & 63) * 4 + h)) * 4096);
  u32x2 bmr[4][2];
#pragma unroll
  for (int tkt = 0; tkt < 4; ++tkt)
#pragma unroll
    for (int j = 0; j < 2; ++j)
      bmr[tkt][j] = *(const u32x2*)(bmb + ((2 * u + j) * 16 + ln) * 128 +
                                    tkt * 32 + g * 8);
  short8 kf[4], qf[2];
#pragma unroll
  for (int t = 0; t < 4; ++t) {
    const unsigned colb = ((unsigned)(g * 16)) ^ key3;
    kf[t] = *(const short8*)(smem + h * 8192 + 4096 + (t * 16 + ln) * 64 + colb);
    if (t < 2)
      qf[t] = *(const short8*)(smem + h * 8192 + ((2 * u + t) * 16 + ln) * 64 + colb);
  }
  __syncthreads();  // B2: all q/k reads done before P overwrites the region
  f32x4 s[4][2];  // [tkt][j]; base-2 exponents (log2e folded in)
#pragma unroll
  for (int tkt = 0; tkt < 4; ++tkt)
#pragma unroll
    for (int j = 0; j < 2; ++j) {
      const f32x4 cin = {bitf(bmr[tkt][j][0] << 16),
                         bitf(bmr[tkt][j][0] & 0xffff0000u),
                         bitf(bmr[tkt][j][1] << 16),
                         bitf(bmr[tkt][j][1] & 0xffff0000u)};
      s[tkt][j] = MFMA16(kf[tkt], qf[j], cin, 0, 0, 0);
    }
  // max-subtract softmax (provably finite: exp2<=1, su in [1,64])
#pragma unroll
  for (int j = 0; j < 2; ++j) {
    const int tq = (2 * u + j) * 16 + ln;
    float m = s[0][j][0];
#pragma unroll
    for (int tkt = 0; tkt < 4; ++tkt)
#pragma unroll
      for (int i = 0; i < 4; ++i) m = fmaxf(m, s[tkt][j][i]);
    m = fmaxf(m, __shfl_xor(m, 16));
    m = fmaxf(m, __shfl_xor(m, 32));
    float su = 0.f;
#pragma unroll
    for (int tkt = 0; tkt < 4; ++tkt)
#pragma unroll
      for (int i = 0; i < 4; ++i) {
        const float p = __builtin_amdgcn_exp2f(s[tkt][j][i] - m);
        s[tkt][j][i] = p;
        su += p;
      }
    su += __shfl_xor(su, 16);
    su += __shfl_xor(su, 32);
    const float rs = __builtin_amdgcn_rcpf(su);  // su >= 1 -> safe
#pragma unroll
    for (int tkt = 0; tkt < 4; ++tkt) {
      const u32x2 d2 = {cvtpk(s[tkt][j][0] * rs, s[tkt][j][1] * rs),
                        cvtpk(s[tkt][j][2] * rs, s[tkt][j][3] * rs)};
      *(u32x2*)(smem + h * 8192 + tq * 128 +
                (((unsigned)(tkt * 32 + g * 8)) ^ key7)) = d2;  // P (normed)
    }
  }

  // ---------------- phase 3: O^T = mfma(v, P), this wave's tq half ------
  short8 vf[2][2], pf[2][2];
#pragma unroll
  for (int Mt = 0; Mt < 2; ++Mt)
#pragma unroll
    for (int kk2 = 0; kk2 < 2; ++kk2)
      vf[Mt][kk2] = *(const short8*)(smem + 32768 + h * 4096 +
                                     (Mt * 16 + ln) * 128 +
                                     (((unsigned)(kk2 * 64 + g * 16)) ^ key7));
#pragma unroll
  for (int j = 0; j < 2; ++j)
#pragma unroll
    for (int kk2 = 0; kk2 < 2; ++kk2)
      pf[j][kk2] = *(const short8*)(smem + h * 8192 +
                                    ((2 * u + j) * 16 + ln) * 128 +
                                    (((unsigned)(kk2 * 64 + g * 16)) ^ key7));
  f32x4 o[2][2];
#pragma unroll
  for (int Mt = 0; Mt < 2; ++Mt)
#pragma unroll
    for (int j = 0; j < 2; ++j) o[Mt][j] = f32x4{0.f, 0.f, 0.f, 0.f};
#pragma unroll
  for (int kk2 = 0; kk2 < 2; ++kk2)
#pragma unroll
    for (int Mt = 0; Mt < 2; ++Mt)
#pragma unroll
      for (int j = 0; j < 2; ++j)
        o[Mt][j] = MFMA16(vf[Mt][kk2], pf[j][kk2], o[Mt][j], 0, 0, 0);
  __syncthreads();  // B3: all VT reads complete before tmp overlays it
#pragma unroll
  for (int Mt = 0; Mt < 2; ++Mt)
#pragma unroll
    for (int j = 0; j < 2; ++j) {
      const int tok = (2 * u + j) * 16 + ln;
      const u32x2 d2 = {cvtpk(o[Mt][j][0], o[Mt][j][1]),
                        cvtpk(o[Mt][j][2], o[Mt][j][3])};
      *(u32x2*)(smem + 32768 + tok * 256 +
                (((unsigned)((h * 32 + Mt * 16 + g * 4) * 2)) ^ key7)) = d2;
    }
  __syncthreads();  // B4: tmp complete

  // ---------------- phase 4: out = mfma(tmp, projW) + proj_b -------------
  // this wave: n-tile = wv (one 16-wide output-channel tile)
  short8 at[4][4];
#pragma unroll
  for (int mt = 0; mt < 4; ++mt)
#pragma unroll
    for (int kk = 0; kk < 4; ++kk)
      at[mt][kk] = *(const short8*)(smem + 32768 + (mt * 16 + ln) * 256 +
                                    (((unsigned)(kk * 64 + g * 16)) ^ key7));
  float* ob = out + (size_t)b * (49 * 128);
  {
    const int n = wv * 16 + ln;
    const float pb = proj_b[n];
    short8 pw[4];
#pragma unroll
    for (int kk = 0; kk < 4; ++kk)
      pw[kk] = *(const short8*)(projw + n * 128 + kk * 32 + g * 8);
    f32x4 acc[4];
#pragma unroll
    for (int mt = 0; mt < 4; ++mt) acc[mt] = f32x4{pb, pb, pb, pb};
#pragma unroll
    for (int kk = 0; kk < 4; ++kk)
#pragma unroll
      for (int mt = 0; mt < 4; ++mt)
        acc[mt] = MFMA16(at[mt][kk], pw[kk], acc[mt], 0, 0, 0);
#pragma unroll
    for (int mt = 0; mt < 4; ++mt)
#pragma unroll
      for (int i = 0; i < 4; ++i) {
        const int row = mt * 16 + g * 4 + i;
        if (row < 49) ob[row * 128 + n] = acc[mt][i];
      }
  }
}

// ---------------------------------------------------------------------------
extern "C" void kernel_launch(void* const* d_in, const int* in_sizes, int n_in,
                              void* d_out, int out_size, void* d_ws,
                              size_t ws_size, hipStream_t stream) {
  const float* x = (const float*)d_in[0];
  const float* mask = (const float*)d_in[1];
  const float* qkv_w = (const float*)d_in[2];
  const float* qkv_b = (const float*)d_in[3];
  const float* proj_w = (const float*)d_in[4];
  const float* proj_b = (const float*)d_in[5];
  const float* rpb = (const float*)d_in[6];
  const int* rel = (const int*)d_in[7];

  u16* qkvw = (u16*)d_ws;
  u16* projw = (u16*)((char*)d_ws + 98304);
  float* qkvbs = (float*)((char*)d_ws + 131072);
  u16* bmsw = (u16*)((char*)d_ws + 133120);  // 2 MB; total ws use ~2.2 MB

  setup_misc<<<4096, 256, 0, stream>>>(qkv_w, qkv_b, proj_w, mask, rpb, rel,
                                       qkvw, projw, qkvbs, bmsw);
  swin_fused<<<4096, 512, 0, stream>>>(x, qkvbs, proj_b, qkvw, projw, bmsw,
                                       (float*)d_out);
}

// Round 10
// 200.127 us; speedup vs baseline: 2.4610x; 2.4610x over previous
//
#include <hip/hip_runtime.h>

typedef __attribute__((ext_vector_type(8))) short short8;
typedef __attribute__((ext_vector_type(4))) float f32x4;
typedef __attribute__((ext_vector_type(2))) unsigned u32x2;
typedef __attribute__((ext_vector_type(4))) unsigned u32x4;
typedef unsigned short u16;

#define MFMA16 __builtin_amdgcn_mfma_f32_16x16x32_bf16

__device__ __forceinline__ u16 f2bf(float f) {
  unsigned u = __builtin_bit_cast(unsigned, f);
  u += 0x7fffu + ((u >> 16) & 1u);  // RTNE
  return (u16)(u >> 16);
}
// R4-proven manual pack (v_cvt_pk_bf16_f32 asm NaN'd in R5/R6 - banned)
__device__ __forceinline__ unsigned cvtpk(float a, float b) {
  return (unsigned)f2bf(a) | ((unsigned)f2bf(b) << 16);
}
__device__ __forceinline__ float bitf(unsigned u) {
  return __builtin_bit_cast(float, u);
}

// ---------------------------------------------------------------------------
// Setup: bf16 weights (q pre-scaled by scale*log2e), scaled bias, bias+mask
// table bmsw[w][h][tq(64)][tk(64)] bf16, pre-multiplied by log2e.
// Sentinel -30000 ONLY for tk>=49 (reduction axis).
// ws: qkvw@0 (98304B) projw@98304 (32768B) qkvbs@131072 (1536B)
//     bmsw@133120 (2097152B)
// ---------------------------------------------------------------------------
__global__ void setup_misc(const float* __restrict__ qkv_w,
                           const float* __restrict__ qkv_b,
                           const float* __restrict__ proj_w,
                           const float* __restrict__ mask,
                           const float* __restrict__ rpb,
                           const int* __restrict__ rel_idx,
                           u16* __restrict__ qkvw, u16* __restrict__ projw,
                           float* __restrict__ qkvbs, u16* __restrict__ bmsw) {
  const int i = blockIdx.x * 256 + threadIdx.x;
  const float LOG2E = 1.44269504088896f;
  const float qsc = 0.17677669529663687f * LOG2E;  // 1/sqrt(32) * log2e
  if (i < 384 * 128) qkvw[i] = f2bf(qkv_w[i] * (i < 16384 ? qsc : 1.f));
  if (i < 128 * 128) projw[i] = f2bf(proj_w[i]);
  if (i < 384) qkvbs[i] = qkv_b[i] * (i < 128 ? qsc : 1.f);
  {  // i in [0,1048576): w=i>>14 h=(i>>12)&3 tq=(i>>6)&63 tk=i&63
    const int w = i >> 14, h = (i >> 12) & 3, tq = (i >> 6) & 63, tk = i & 63;
    float v = 0.f;
    if (tk >= 49)
      v = -30000.f;  // mask the reduction axis only
    else if (tq < 49)
      v = (rpb[rel_idx[tq * 49 + tk] * 4 + h] + mask[w * 2401 + tq * 49 + tk]) *
          LOG2E;
    bmsw[i] = f2bf(v);
  }
}

// ---------------------------------------------------------------------------
// Fused Swin block. 1 block = 1 window, 8 waves: wave (h,u) = head h, half u.
// Per wave: phase1 3 GEMM tiles; phase2 S^T columns tqt in {2u,2u+1};
// phase3 matching PV half; phase4 one n-tile of the out-proj.
// __launch_bounds__(512,4): VGPR cap 128 (4 waves/SIMD tier). (512,6) forced
// the compiler toward the 64-VGPR tier -> full aa[] spill, 1.7GB scratch
// traffic (R9 lesson: occupancy tiers step at VGPR=64/128/256, no 85 tier).
// LDS (49152 B), all rows XOR-swizzled (key row-determined both sides):
//  qT[h] @ h*8192        : [64 tok][64B: 32 d]   key=(row&3)<<4
//  kT[h] @ h*8192+4096   : [64 tok][64B: 32 d]   key=(row&3)<<4
//  P[h]  @ h*8192        : [64 tq][128B: 64 tk]  key=(row&7)<<4 (alias qT||kT)
//  VT[h] @ 32768+h*4096  : [32 d][128B: 64 tk]   key=(row&7)<<4
//  tmp   @ 32768         : [64 tok][256B: 128ch] key=(row&7)<<4 (alias all VT)
// ---------------------------------------------------------------------------
__global__ __launch_bounds__(512, 4) void swin_fused(
    const float* __restrict__ x, const float* __restrict__ qkvbs,
    const float* __restrict__ proj_b, const u16* __restrict__ qkvw,
    const u16* __restrict__ projw, const u16* __restrict__ bmsw,
    float* __restrict__ out) {
  __shared__ __align__(16) char smem[49152];
  const int b = blockIdx.x;
  const int tid = threadIdx.x;
  const int wv = tid >> 6;   // 0..7
  const int h = wv >> 1;     // head
  const int u = wv & 1;      // half
  const int lane = tid & 63;
  const int g = lane >> 4;
  const int ln = lane & 15;
  const unsigned key3 = (unsigned)((ln & 3) << 4);
  const unsigned key7 = (unsigned)((ln & 7) << 4);

  // ---------------- phase 1: x frags (A for v, B for q/k) ----------------
  short8 aa[4][4];
  const float* xb = x + (size_t)b * (49 * 128);
#pragma unroll
  for (int mt = 0; mt < 4; ++mt) {
    const int row = mt * 16 + ln;
#pragma unroll
    for (int kk = 0; kk < 4; ++kk) {
      if (row < 49) {
        const float* p = xb + row * 128 + kk * 32 + g * 8;
        const f32x4 u0 = *(const f32x4*)p;
        const f32x4 u1 = *(const f32x4*)(p + 4);
        u32x4 r = {cvtpk(u0[0], u0[1]), cvtpk(u0[2], u0[3]),
                   cvtpk(u1[0], u1[1]), cvtpk(u1[2], u1[3])};
        aa[mt][kk] = __builtin_bit_cast(short8, r);
      } else {
        u32x4 r = {0u, 0u, 0u, 0u};
        aa[mt][kk] = __builtin_bit_cast(short8, r);
      }
    }
  }
  // q^T, k^T: C[ch][tok] = mfma(W, x); this wave does Mt = u only
#pragma unroll
  for (int qk = 0; qk < 2; ++qk) {
    const int n = qk * 128 + h * 32 + u * 16 + ln;
    short8 wf[4];
#pragma unroll
    for (int kk = 0; kk < 4; ++kk)
      wf[kk] = *(const short8*)(qkvw + n * 128 + kk * 32 + g * 8);
    const f32x4 bq = *(const f32x4*)(qkvbs + qk * 128 + h * 32 + u * 16 + g * 4);
    f32x4 acc[4];
#pragma unroll
    for (int Nt = 0; Nt < 4; ++Nt) acc[Nt] = bq;
#pragma unroll
    for (int kk = 0; kk < 4; ++kk)
#pragma unroll
      for (int Nt = 0; Nt < 4; ++Nt)
        acc[Nt] = MFMA16(wf[kk], aa[Nt][kk], acc[Nt], 0, 0, 0);
#pragma unroll
    for (int Nt = 0; Nt < 4; ++Nt) {
      const int tok = Nt * 16 + ln;
      const u32x2 d2 = {cvtpk(acc[Nt][0], acc[Nt][1]),
                        cvtpk(acc[Nt][2], acc[Nt][3])};
      *(u32x2*)(smem + h * 8192 + qk * 4096 + tok * 64 +
                (((unsigned)(u * 32 + g * 8)) ^ key3)) = d2;
    }
  }
  // v: C[tok][d] = mfma(x, W) -> store VT[d][tok]; this wave dt = u
  {
    const int n = 256 + h * 32 + u * 16 + ln;
    short8 wf[4];
#pragma unroll
    for (int kk = 0; kk < 4; ++kk)
      wf[kk] = *(const short8*)(qkvw + n * 128 + kk * 32 + g * 8);
    const float bv = qkvbs[n];
    f32x4 acc[4];
#pragma unroll
    for (int mt = 0; mt < 4; ++mt) acc[mt] = f32x4{bv, bv, bv, bv};
#pragma unroll
    for (int kk = 0; kk < 4; ++kk)
#pragma unroll
      for (int mt = 0; mt < 4; ++mt)
        acc[mt] = MFMA16(aa[mt][kk], wf[kk], acc[mt], 0, 0, 0);
    const int d = u * 16 + ln;
#pragma unroll
    for (int mt = 0; mt < 4; ++mt) {
      const u32x2 d2 = {cvtpk(acc[mt][0], acc[mt][1]),
                        cvtpk(acc[mt][2], acc[mt][3])};
      *(u32x2*)(smem + 32768 + h * 4096 + d * 128 +
                (((unsigned)(mt * 32 + g * 8)) ^ key7)) = d2;
    }
  }
  __syncthreads();  // B1: q/k/VT complete (written by wave pairs)

  // ---------------- phase 2: S^T = mfma(k, q) + bias-as-C-init ----------
  // this wave: tqt = 2u + j, j in {0,1}
  const char* bmb = (const char*)(bmsw + ((size_t)((b & 63) * 4 + h)) * 4096);
  u32x2 bmr[4][2];
#pragma unroll
  for (int tkt = 0; tkt < 4; ++tkt)
#pragma unroll
    for (int j = 0; j < 2; ++j)
      bmr[tkt][j] = *(const u32x2*)(bmb + ((2 * u + j) * 16 + ln) * 128 +
                                    tkt * 32 + g * 8);
  short8 kf[4], qf[2];
#pragma unroll
  for (int t = 0; t < 4; ++t) {
    const unsigned colb = ((unsigned)(g * 16)) ^ key3;
    kf[t] = *(const short8*)(smem + h * 8192 + 4096 + (t * 16 + ln) * 64 + colb);
    if (t < 2)
      qf[t] = *(const short8*)(smem + h * 8192 + ((2 * u + t) * 16 + ln) * 64 + colb);
  }
  __syncthreads();  // B2: all q/k reads done before P overwrites the region
  f32x4 s[4][2];  // [tkt][j]; base-2 exponents (log2e folded in)
#pragma unroll
  for (int tkt = 0; tkt < 4; ++tkt)
#pragma unroll
    for (int j = 0; j < 2; ++j) {
      const f32x4 cin = {bitf(bmr[tkt][j][0] << 16),
                         bitf(bmr[tkt][j][0] & 0xffff0000u),
                         bitf(bmr[tkt][j][1] << 16),
                         bitf(bmr[tkt][j][1] & 0xffff0000u)};
      s[tkt][j] = MFMA16(kf[tkt], qf[j], cin, 0, 0, 0);
    }
  // max-subtract softmax (provably finite: exp2<=1, su in [1,64])
#pragma unroll
  for (int j = 0; j < 2; ++j) {
    const int tq = (2 * u + j) * 16 + ln;
    float m = s[0][j][0];
#pragma unroll
    for (int tkt = 0; tkt < 4; ++tkt)
#pragma unroll
      for (int i = 0; i < 4; ++i) m = fmaxf(m, s[tkt][j][i]);
    m = fmaxf(m, __shfl_xor(m, 16));
    m = fmaxf(m, __shfl_xor(m, 32));
    float su = 0.f;
#pragma unroll
    for (int tkt = 0; tkt < 4; ++tkt)
#pragma unroll
      for (int i = 0; i < 4; ++i) {
        const float p = __builtin_amdgcn_exp2f(s[tkt][j][i] - m);
        s[tkt][j][i] = p;
        su += p;
      }
    su += __shfl_xor(su, 16);
    su += __shfl_xor(su, 32);
    const float rs = __builtin_amdgcn_rcpf(su);  // su >= 1 -> safe
#pragma unroll
    for (int tkt = 0; tkt < 4; ++tkt) {
      const u32x2 d2 = {cvtpk(s[tkt][j][0] * rs, s[tkt][j][1] * rs),
                        cvtpk(s[tkt][j][2] * rs, s[tkt][j][3] * rs)};
      *(u32x2*)(smem + h * 8192 + tq * 128 +
                (((unsigned)(tkt * 32 + g * 8)) ^ key7)) = d2;  // P (normed)
    }
  }

  // ---------------- phase 3: O^T = mfma(v, P), this wave's tq half ------
  short8 vf[2][2], pf[2][2];
#pragma unroll
  for (int Mt = 0; Mt < 2; ++Mt)
#pragma unroll
    for (int kk2 = 0; kk2 < 2; ++kk2)
      vf[Mt][kk2] = *(const short8*)(smem + 32768 + h * 4096 +
                                     (Mt * 16 + ln) * 128 +
                                     (((unsigned)(kk2 * 64 + g * 16)) ^ key7));
#pragma unroll
  for (int j = 0; j < 2; ++j)
#pragma unroll
    for (int kk2 = 0; kk2 < 2; ++kk2)
      pf[j][kk2] = *(const short8*)(smem + h * 8192 +
                                    ((2 * u + j) * 16 + ln) * 128 +
                                    (((unsigned)(kk2 * 64 + g * 16)) ^ key7));
  f32x4 o[2][2];
#pragma unroll
  for (int Mt = 0; Mt < 2; ++Mt)
#pragma unroll
    for (int j = 0; j < 2; ++j) o[Mt][j] = f32x4{0.f, 0.f, 0.f, 0.f};
#pragma unroll
  for (int kk2 = 0; kk2 < 2; ++kk2)
#pragma unroll
    for (int Mt = 0; Mt < 2; ++Mt)
#pragma unroll
      for (int j = 0; j < 2; ++j)
        o[Mt][j] = MFMA16(vf[Mt][kk2], pf[j][kk2], o[Mt][j], 0, 0, 0);
  __syncthreads();  // B3: all VT reads complete before tmp overlays it
#pragma unroll
  for (int Mt = 0; Mt < 2; ++Mt)
#pragma unroll
    for (int j = 0; j < 2; ++j) {
      const int tok = (2 * u + j) * 16 + ln;
      const u32x2 d2 = {cvtpk(o[Mt][j][0], o[Mt][j][1]),
                        cvtpk(o[Mt][j][2], o[Mt][j][3])};
      *(u32x2*)(smem + 32768 + tok * 256 +
                (((unsigned)((h * 32 + Mt * 16 + g * 4) * 2)) ^ key7)) = d2;
    }
  __syncthreads();  // B4: tmp complete

  // ---------------- phase 4: out = mfma(tmp, projW) + proj_b -------------
  // this wave: n-tile = wv (one 16-wide output-channel tile)
  short8 at[4][4];
#pragma unroll
  for (int mt = 0; mt < 4; ++mt)
#pragma unroll
    for (int kk = 0; kk < 4; ++kk)
      at[mt][kk] = *(const short8*)(smem + 32768 + (mt * 16 + ln) * 256 +
                                    (((unsigned)(kk * 64 + g * 16)) ^ key7));
  float* ob = out + (size_t)b * (49 * 128);
  {
    const int n = wv * 16 + ln;
    const float pb = proj_b[n];
    short8 pw[4];
#pragma unroll
    for (int kk = 0; kk < 4; ++kk)
      pw[kk] = *(const short8*)(projw + n * 128 + kk * 32 + g * 8);
    f32x4 acc[4];
#pragma unroll
    for (int mt = 0; mt < 4; ++mt) acc[mt] = f32x4{pb, pb, pb, pb};
#pragma unroll
    for (int kk = 0; kk < 4; ++kk)
#pragma unroll
      for (int mt = 0; mt < 4; ++mt)
        acc[mt] = MFMA16(at[mt][kk], pw[kk], acc[mt], 0, 0, 0);
#pragma unroll
    for (int mt = 0; mt < 4; ++mt)
#pragma unroll
      for (int i = 0; i < 4; ++i) {
        const int row = mt * 16 + g * 4 + i;
        if (row < 49) ob[row * 128 + n] = acc[mt][i];
      }
  }
}

// ---------------------------------------------------------------------------
extern "C" void kernel_launch(void* const* d_in, const int* in_sizes, int n_in,
                              void* d_out, int out_size, void* d_ws,
                              size_t ws_size, hipStream_t stream) {
  const float* x = (const float*)d_in[0];
  const float* mask = (const float*)d_in[1];
  const float* qkv_w = (const float*)d_in[2];
  const float* qkv_b = (const float*)d_in[3];
  const float* proj_w = (const float*)d_in[4];
  const float* proj_b = (const float*)d_in[5];
  const float* rpb = (const float*)d_in[6];
  const int* rel = (const int*)d_in[7];

  u16* qkvw = (u16*)d_ws;
  u16* projw = (u16*)((char*)d_ws + 98304);
  float* qkvbs = (float*)((char*)d_ws + 131072);
  u16* bmsw = (u16*)((char*)d_ws + 133120);  // 2 MB; total ws use ~2.2 MB

  setup_misc<<<4096, 256, 0, stream>>>(qkv_w, qkv_b, proj_w, mask, rpb, rel,
                                       qkvw, projw, qkvbs, bmsw);
  swin_fused<<<4096, 512, 0, stream>>>(x, qkvbs, proj_b, qkvw, projw, bmsw,
                                       (float*)d_out);
}